// Round 7
// baseline (305.547 us; speedup 1.0000x reference)
//
#include <hip/hip_runtime.h>
#include <math.h>

#define B_ 64
#define N_ 512
#define P_ 256
#define E_ 4096
#define F_ 32
#define H_ 64
#define W_ 8
#define G_ 64
#define RH_ 256

// ---- workspace layout (float offsets) ----
#define X_OFF   0
#define T4_OFF  (X_OFF + N_*B_*F_)       // x:  [n][b][f]
#define T3_OFF  (T4_OFF + N_*B_*H_)      // t4: [n][b][h] (t2 folded in)
#define KB_OFF  (T3_OFF + P_*B_*H_)      // t3: [p][b][h]
#define KW_OFF  (KB_OFF + E_*H_)         // kb: [e][h]
#define YG_OFF  (KW_OFF + E_*B_*W_)      // kw_s: [pos][b][w] (sorted by partition)
#define HB_OFF  (YG_OFF + B_*P_*G_)      // yg: [b][p*64+g]
#define RES_OFF (HB_OFF + B_*RH_)        // hbuf: [b][rh]
#define INT_OFF (RES_OFF + 4*B_*G_)      // res4: [pq][b][g]
#define PART_OFF (INT_OFF + 20480)       // r0 partials: [512][16384] floats
// int region at INT_OFF: lidx[4096] | ridx[4096] | part_start[512] | part_edges[4096] | r_s[4096]

// ---------------------------------------------------------------------------
// blocks [0,3072): decode one-hots; [3072,3584): grouped conv
__global__ __launch_bounds__(256) void k_dc(const float* __restrict__ linc,
    const float* __restrict__ rinc, int* __restrict__ lidx, int* __restrict__ ridx,
    const float* __restrict__ x1, const float* __restrict__ conv_w,
    const float* __restrict__ conv_b, float* __restrict__ x) {
  __shared__ float wsm[32 * 132];
  __shared__ float xsm[8192];
  int blk = blockIdx.x, t = threadIdx.x;
  if (blk < 3072) {
    int i4 = blk * 256 + t;
    const int L4 = (P_ * E_) / 4;  // 262144
    if (i4 < L4) {
      float4 v = ((const float4*)linc)[i4];
      int i = i4 * 4;
      int p = i >> 12, e = i & 4095;
      if (v.x != 0.0f) lidx[e]     = p;
      if (v.y != 0.0f) lidx[e + 1] = p;
      if (v.z != 0.0f) lidx[e + 2] = p;
      if (v.w != 0.0f) lidx[e + 3] = p;
    } else {
      int j4 = i4 - L4;
      float4 v = ((const float4*)rinc)[j4];
      int j = j4 * 4;
      int e = j >> 9, n = j & 511;
      if (v.x != 0.0f) ridx[e] = n;
      if (v.y != 0.0f) ridx[e] = n + 1;
      if (v.z != 0.0f) ridx[e] = n + 2;
      if (v.w != 0.0f) ridx[e] = n + 3;
    }
    return;
  }
  int n = blk - 3072;
  for (int i = t; i < 1024; i += 256) {
    int f = i >> 5, j = i & 31;
    ((float4*)wsm)[f * 33 + j] = ((const float4*)(conv_w + n * 4096))[i];
  }
  for (int i = t; i < 2048; i += 256) {
    int b = i >> 5, j = i & 31;
    ((float4*)xsm)[i] = ((const float4*)(x1 + b * 65536 + n * 128))[j];
  }
  __syncthreads();
  int f = t & 31, bq = t >> 5;
  float cb = conv_b[n * 32 + f];
  float acc[8];
#pragma unroll
  for (int bi = 0; bi < 8; bi++) acc[bi] = cb;
  const float4* wf4 = (const float4*)wsm + f * 33;
  const float4* xb4 = (const float4*)xsm + bq * 256;
#pragma unroll 4
  for (int k4 = 0; k4 < 32; k4++) {
    float4 wv = wf4[k4];
#pragma unroll
    for (int bi = 0; bi < 8; bi++) {
      float4 xv = xb4[bi * 32 + k4];
      acc[bi] += wv.x * xv.x + wv.y * xv.y + wv.z * xv.z + wv.w * xv.w;
    }
  }
#pragma unroll
  for (int bi = 0; bi < 8; bi++) {
    int b = bq * 8 + bi;
    x[n * 2048 + b * 32 + f] = fmaxf(acc[bi], 0.0f);
  }
}

// Counting-sort edges by partition; also emit r_s[pos] = ridx[part_edges[pos]].
__global__ __launch_bounds__(1024) void k_lists(const int* __restrict__ lidx,
    const int* __restrict__ ridx, int* __restrict__ part_start,
    int* __restrict__ part_edges, int* __restrict__ r_s) {
  __shared__ int cnt[256];
  __shared__ int buf[256];
  __shared__ int cur[256];
  int t = threadIdx.x;
  if (t < 256) cnt[t] = 0;
  __syncthreads();
  for (int e = t; e < E_; e += 1024) atomicAdd(&cnt[lidx[e]], 1);
  __syncthreads();
  if (t < 256) buf[t] = cnt[t];
  __syncthreads();
  for (int off = 1; off < 256; off <<= 1) {
    int add = 0;
    if (t < 256 && t >= off) add = buf[t - off];
    __syncthreads();
    if (t < 256) buf[t] += add;
    __syncthreads();
  }
  if (t < 256) {
    part_start[t + 1] = buf[t];
    if (t == 0) part_start[0] = 0;
    cur[t] = buf[t] - cnt[t];
  }
  __syncthreads();
  for (int e = t; e < E_; e += 1024) {
    int p = lidx[e];
    int pos = atomicAdd(&cur[p], 1);
    part_edges[pos] = e;
  }
  __syncthreads();
  for (int pos = t; pos < E_; pos += 1024) r_s[pos] = ridx[part_edges[pos]];
}

// blocks [0,512): t4[n][b][h] = x[n]@k4_w^T + x2@k2_w^T
// blocks [512,768): t3[p][b][h] = x[pidx[p]]@k3_w^T
// blocks [768,1792): kb[e][h] = ef[e,:8]@k1_w^T + k1_b
// blocks [1792,1856): hbuf[b][rh] = x2@r1_w^T + r1_b + cap@r2_w^T
__global__ __launch_bounds__(256) void k_prep(
    const float* __restrict__ x, const int* __restrict__ pidx,
    const float* __restrict__ k3_w, const float* __restrict__ k4_w,
    const float* __restrict__ x2, const float* __restrict__ k2_w,
    const float* __restrict__ ef, const float* __restrict__ k1_w,
    const float* __restrict__ k1_b,
    const float* __restrict__ r1_w, const float* __restrict__ r1_b,
    const float* __restrict__ r2_w, const float* __restrict__ cap,
    float* __restrict__ t4, float* __restrict__ t3, float* __restrict__ kb,
    float* __restrict__ hbuf) {
  __shared__ float xsh[2048];
  __shared__ float wsh[64 * 36];
  __shared__ float x2s[512];
  __shared__ float k2s[512];
  int blk = blockIdx.x, t = threadIdx.x;
  if (blk < 768) {
    bool isT4 = blk < 512;
    int n = isT4 ? blk : pidx[blk - 512];
    const float* wmat = isT4 ? k4_w : k3_w;
    float* outp = isT4 ? (t4 + blk * 4096) : (t3 + (blk - 512) * 4096);
    for (int i = t; i < 512; i += 256) {
      ((float4*)xsh)[i] = ((const float4*)(x + n * 2048))[i];
      int h = i >> 3, j = i & 7;
      ((float4*)wsh)[h * 9 + j] = ((const float4*)wmat)[i];
    }
    if (isT4) {
      for (int i = t; i < 128; i += 256) {
        ((float4*)x2s)[i] = ((const float4*)x2)[i];
        ((float4*)k2s)[i] = ((const float4*)k2_w)[i];
      }
    }
    __syncthreads();
    int h = t & 63, bq = t >> 6;
    float wreg[32];
#pragma unroll
    for (int j = 0; j < 8; j++) {
      float4 v = ((float4*)wsh)[h * 9 + j];
      wreg[4 * j] = v.x; wreg[4 * j + 1] = v.y; wreg[4 * j + 2] = v.z; wreg[4 * j + 3] = v.w;
    }
    float w2[8];
    if (isT4) {
      float4 u = ((float4*)k2s)[h * 2], v = ((float4*)k2s)[h * 2 + 1];
      w2[0] = u.x; w2[1] = u.y; w2[2] = u.z; w2[3] = u.w;
      w2[4] = v.x; w2[5] = v.y; w2[6] = v.z; w2[7] = v.w;
    }
    for (int bi = 0; bi < 16; bi++) {
      int b = bq * 16 + bi;
      float acc = 0.0f;
#pragma unroll
      for (int j = 0; j < 8; j++) {
        float4 xv = ((float4*)xsh)[b * 8 + j];
        acc += xv.x * wreg[4 * j] + xv.y * wreg[4 * j + 1] +
               xv.z * wreg[4 * j + 2] + xv.w * wreg[4 * j + 3];
      }
      if (isT4) {
        float4 u = ((float4*)x2s)[b * 2], v = ((float4*)x2s)[b * 2 + 1];
        acc += u.x * w2[0] + u.y * w2[1] + u.z * w2[2] + u.w * w2[3] +
               v.x * w2[4] + v.y * w2[5] + v.z * w2[6] + v.w * w2[7];
      }
      outp[b * 64 + h] = acc;
    }
  } else if (blk < 1792) {
    int o = (blk - 768) * 256 + t;
    int e = o >> 6, h = o & 63;
    float acc = k1_b[h];
    const float* er = ef + e * 9;
    const float* kr = k1_w + h * 8;
#pragma unroll
    for (int d = 0; d < 8; d++) acc += er[d] * kr[d];
    kb[o] = acc;
  } else {
    int o = (blk - 1792) * 256 + t;
    int rh = o & 255;
    float acc = r1_b[rh];
    const float* xr = x2 + (o >> 8) * 8;
    const float* rr = r1_w + rh * 8;
#pragma unroll
    for (int d = 0; d < 8; d++) acc += xr[d] * rr[d];
    const float* r2r = r2_w + rh * 256;
    for (int p4 = 0; p4 < 64; p4++) {
      float4 cv = ((const float4*)cap)[p4];
      float4 rv = ((const float4*)r2r)[p4];
      acc += cv.x * rv.x + cv.y * rv.y + cv.z * rv.z + cv.w * rv.w;
    }
    hbuf[o] = acc;
  }
}

// Phase A: per-edge kernel weights. 4 sorted positions per block.
// kern = kb[e]+t3[lidx]+t4[ridx]; leaky(0.02); @k5_w^T + k5_b; relu
// -> kw_s[pos][b][w] (partition-sorted order).
__global__ __launch_bounds__(256) void k_edge(
    const float* __restrict__ kb, const float* __restrict__ t3,
    const float* __restrict__ t4, const float* __restrict__ k5_w,
    const float* __restrict__ k5_b, const int* __restrict__ lidx,
    const int* __restrict__ ridx, const int* __restrict__ part_edges,
    float* __restrict__ kw_s) {
  __shared__ float k5t[4 * 520];
  int pos0 = blockIdx.x * 4, t = threadIdx.x;
  for (int i = t; i < 512; i += 256) {
    int h = i >> 3, w = i & 7;
    float v = k5_w[w * 64 + h];
#pragma unroll
    for (int qq = 0; qq < 4; qq++) k5t[qq * 520 + i] = v;
  }
  int q = t & 3, b = t >> 2;
  const float* kq = k5t + q * 520 + q * 128;
  float kb5_0 = k5_b[2 * q], kb5_1 = k5_b[2 * q + 1];
  __syncthreads();
  for (int ei = 0; ei < 4; ei++) {
    int pos = pos0 + ei;
    int e = part_edges[pos];
    int p = lidx[e], r = ridx[e];
    const float4* kb4 = (const float4*)(kb + e * 64 + q * 16);
    const float4* t34 = (const float4*)(t3 + p * 4096 + b * 64 + q * 16);
    const float4* t44 = (const float4*)(t4 + r * 4096 + b * 64 + q * 16);
    float lk[16];
#pragma unroll
    for (int j4 = 0; j4 < 4; j4++) {
      float4 a = kb4[j4], c = t34[j4], d = t44[j4];
      float v;
      v = a.x + c.x + d.x; lk[j4 * 4 + 0] = v > 0.0f ? v : 0.02f * v;
      v = a.y + c.y + d.y; lk[j4 * 4 + 1] = v > 0.0f ? v : 0.02f * v;
      v = a.z + c.z + d.z; lk[j4 * 4 + 2] = v > 0.0f ? v : 0.02f * v;
      v = a.w + c.w + d.w; lk[j4 * 4 + 3] = v > 0.0f ? v : 0.02f * v;
    }
    float pw[8] = {0, 0, 0, 0, 0, 0, 0, 0};
#pragma unroll
    for (int j = 0; j < 16; j++) {
      float4 u = *(const float4*)(kq + j * 8);
      float4 v = *(const float4*)(kq + j * 8 + 4);
      float l = lk[j];
      pw[0] += l * u.x; pw[1] += l * u.y; pw[2] += l * u.z; pw[3] += l * u.w;
      pw[4] += l * v.x; pw[5] += l * v.y; pw[6] += l * v.z; pw[7] += l * v.w;
    }
#pragma unroll
    for (int w = 0; w < 8; w++) {
      pw[w] += __shfl_xor(pw[w], 1);
      pw[w] += __shfl_xor(pw[w], 2);
    }
    float2 o;
    o.x = fmaxf(pw[2 * q] + kb5_0, 0.0f);
    o.y = fmaxf(pw[2 * q + 1] + kb5_1, 0.0f);
    *(float2*)(kw_s + pos * 512 + t * 2) = o;
  }
}

// Phase B: aggregation + gc GEMM. Grid 1024 = bsub(4 hi) x p(256 lo); 16 b per block.
// Thread (bl = t>>4, s = t&15): acc[16] = k-range [s*16, s*16+16) (w = s>>1, fh = s&1).
// Edge loop in groups of 4: r_s/kw batched (no serial chain), 4-deep load pipelining.
// fp32 accS, oct ^ ((bl>>1)&3) swizzle; epilogue 2b x 2g register tiles, 4 blocks/CU.
__global__ __launch_bounds__(256) void k_agg(
    const float* __restrict__ x, const float* __restrict__ kw_s,
    const int* __restrict__ r_s, const int* __restrict__ part_start,
    const float* __restrict__ gc_w, const float* __restrict__ gc_b,
    float* __restrict__ yg) {
  __shared__ float accS[16 * 256];  // fp32 [bl][k]; oct at (oct ^ ((bl>>1)&3))*8
  int blk = blockIdx.x, t = threadIdx.x;
  int p = blk & 255, bsub = blk >> 8;   // bsub in [0,4)
  int bl = t >> 4, s = t & 15;
  int b = bsub * 16 + bl;
  int w = s >> 1, fh = s & 1;
  float acc[16];
#pragma unroll
  for (int j = 0; j < 16; j++) acc[j] = 0.0f;
  int s0 = part_start[p], s1 = part_start[p + 1];
  const float* xb = x + b * 32 + fh * 16;
  const float* kwp = kw_s + b * 8 + w;
  int pos = s0;
  for (; pos + 3 < s1; pos += 4) {
    int rr[4];
    float kvv[4];
    rr[0] = r_s[pos];     rr[1] = r_s[pos + 1];
    rr[2] = r_s[pos + 2]; rr[3] = r_s[pos + 3];
    kvv[0] = kwp[(pos) * 512];     kvv[1] = kwp[(pos + 1) * 512];
    kvv[2] = kwp[(pos + 2) * 512]; kvv[3] = kwp[(pos + 3) * 512];
#pragma unroll
    for (int i = 0; i < 4; i++) {
      const float4* xp = (const float4*)(xb + rr[i] * 2048);
      float4 x0 = xp[0], x1 = xp[1], x2 = xp[2], x3 = xp[3];
      float kv = kvv[i];
      acc[0]  += kv * x0.x; acc[1]  += kv * x0.y; acc[2]  += kv * x0.z; acc[3]  += kv * x0.w;
      acc[4]  += kv * x1.x; acc[5]  += kv * x1.y; acc[6]  += kv * x1.z; acc[7]  += kv * x1.w;
      acc[8]  += kv * x2.x; acc[9]  += kv * x2.y; acc[10] += kv * x2.z; acc[11] += kv * x2.w;
      acc[12] += kv * x3.x; acc[13] += kv * x3.y; acc[14] += kv * x3.z; acc[15] += kv * x3.w;
    }
  }
  for (; pos < s1; pos++) {
    int r = r_s[pos];
    float kv = kwp[pos * 512];
    const float4* xp = (const float4*)(xb + r * 2048);
    float4 x0 = xp[0], x1 = xp[1], x2 = xp[2], x3 = xp[3];
    acc[0]  += kv * x0.x; acc[1]  += kv * x0.y; acc[2]  += kv * x0.z; acc[3]  += kv * x0.w;
    acc[4]  += kv * x1.x; acc[5]  += kv * x1.y; acc[6]  += kv * x1.z; acc[7]  += kv * x1.w;
    acc[8]  += kv * x2.x; acc[9]  += kv * x2.y; acc[10] += kv * x2.z; acc[11] += kv * x2.w;
    acc[12] += kv * x3.x; acc[13] += kv * x3.y; acc[14] += kv * x3.z; acc[15] += kv * x3.w;
  }
  // store acc -> accS (k octs 2s, 2s+1), swizzled
  int swz = (bl >> 1) & 3;
#pragma unroll
  for (int j = 0; j < 2; j++) {
    int oct = s * 2 + j;
    int os = oct ^ swz;
    float* dst = accS + bl * 256 + os * 8;
    *(float4*)dst = make_float4(acc[j * 8], acc[j * 8 + 1], acc[j * 8 + 2], acc[j * 8 + 3]);
    *(float4*)(dst + 4) =
        make_float4(acc[j * 8 + 4], acc[j * 8 + 5], acc[j * 8 + 6], acc[j * 8 + 7]);
  }
  __syncthreads();
  // epilogue: wave wv -> g0 = wv*16 + gg*2; lane q = lane>>3 -> rows 2q, 2q+1
  int lane = t & 63, wv = t >> 6;
  int q = lane >> 3, gg = lane & 7;
  int g0 = wv * 16 + gg * 2;
  const float* gw0 = gc_w + g0 * 256;
  const float* gw1 = gw0 + 256;
  float ac00 = 0.0f, ac01 = 0.0f, ac10 = 0.0f, ac11 = 0.0f;
  int row0 = q * 2, row1 = q * 2 + 1;
  int sz = q & 3;  // == (row0>>1)&3 == (row1>>1)&3
  for (int oct = 0; oct < 32; oct++) {
    int os = oct ^ sz;
    const float* s0p = accS + row0 * 256 + os * 8;
    const float* s1p = accS + row1 * 256 + os * 8;
    float4 a0a = *(const float4*)s0p, a0b = *(const float4*)(s0p + 4);
    float4 a1a = *(const float4*)s1p, a1b = *(const float4*)(s1p + 4);
    float4 b0a = *(const float4*)(gw0 + oct * 8), b0b = *(const float4*)(gw0 + oct * 8 + 4);
    float4 b1a = *(const float4*)(gw1 + oct * 8), b1b = *(const float4*)(gw1 + oct * 8 + 4);
    float av0[8] = {a0a.x, a0a.y, a0a.z, a0a.w, a0b.x, a0b.y, a0b.z, a0b.w};
    float av1[8] = {a1a.x, a1a.y, a1a.z, a1a.w, a1b.x, a1b.y, a1b.z, a1b.w};
    float bv0[8] = {b0a.x, b0a.y, b0a.z, b0a.w, b0b.x, b0b.y, b0b.z, b0b.w};
    float bv1[8] = {b1a.x, b1a.y, b1a.z, b1a.w, b1b.x, b1b.y, b1b.z, b1b.w};
#pragma unroll
    for (int kk = 0; kk < 8; kk++) {
      ac00 += av0[kk] * bv0[kk]; ac01 += av0[kk] * bv1[kk];
      ac10 += av1[kk] * bv0[kk]; ac11 += av1[kk] * bv1[kk];
    }
  }
  float gb0 = gc_b[g0], gb1 = gc_b[g0 + 1];
  int b0 = bsub * 16 + row0, b1 = bsub * 16 + row1;
  float2 o0, o1;
  o0.x = fmaxf(ac00 + gb0, 0.0f); o0.y = fmaxf(ac01 + gb1, 0.0f);
  o1.x = fmaxf(ac10 + gb0, 0.0f); o1.y = fmaxf(ac11 + gb1, 0.0f);
  *(float2*)(yg + b0 * 16384 + p * 64 + g0) = o0;
  *(float2*)(yg + b1 * 16384 + p * 64 + g0) = o1;
}

// r0 GEMM partials: grid 512 = kc (Kc=32). Block computes full 64b x 256rh tile
// for its 32-k chunk via outer product; writes part[kc][b][rh].
__global__ __launch_bounds__(256) void k_r0(const float* __restrict__ yg,
    const float* __restrict__ r0_w, float* __restrict__ part) {
  __shared__ float ygs[32 * 69];   // ygT[k][b], row stride 69
  __shared__ float wts[32 * 260];  // wT[k][rh], row stride 260
  int kc = blockIdx.x, t = threadIdx.x;
  int k0 = kc * 32;
  {
    int c = t >> 5, rr = t & 31;
    for (int rd = 0; rd < 8; rd++) {
      int rh = rd * 32 + rr;
      float4 v = *(const float4*)(r0_w + rh * 16384 + k0 + c * 4);
      wts[(4 * c + 0) * 260 + rh] = v.x;
      wts[(4 * c + 1) * 260 + rh] = v.y;
      wts[(4 * c + 2) * 260 + rh] = v.z;
      wts[(4 * c + 3) * 260 + rh] = v.w;
    }
  }
  {
    int b = t >> 2, kq = t & 3;
    const float* src = yg + b * 16384 + k0 + kq * 8;
#pragma unroll
    for (int uu = 0; uu < 2; uu++) {
      float4 v = *(const float4*)(src + uu * 4);
      int kk = kq * 8 + uu * 4;
      ygs[(kk + 0) * 69 + b] = v.x;
      ygs[(kk + 1) * 69 + b] = v.y;
      ygs[(kk + 2) * 69 + b] = v.z;
      ygs[(kk + 3) * 69 + b] = v.w;
    }
  }
  __syncthreads();
  int lane = t & 63, wv = t >> 6;
  int b8 = lane & 7, r8 = lane >> 3;
  const float* yp = ygs + b8 * 8;
  const float* wp = wts + wv * 64 + r8 * 8;
  float acc[8][8];
#pragma unroll
  for (int i = 0; i < 8; i++)
#pragma unroll
    for (int j = 0; j < 8; j++) acc[i][j] = 0.0f;
#pragma unroll 2
  for (int k = 0; k < 32; k++) {
    float4 ya = *(const float4*)(yp + k * 69);
    float4 yb = *(const float4*)(yp + k * 69 + 4);
    float4 wa = *(const float4*)(wp + k * 260);
    float4 wb = *(const float4*)(wp + k * 260 + 4);
    float yv[8] = {ya.x, ya.y, ya.z, ya.w, yb.x, yb.y, yb.z, yb.w};
    float wr[8] = {wa.x, wa.y, wa.z, wa.w, wb.x, wb.y, wb.z, wb.w};
#pragma unroll
    for (int i = 0; i < 8; i++)
#pragma unroll
      for (int j = 0; j < 8; j++) acc[i][j] += yv[i] * wr[j];
  }
  float* pb = part + kc * 16384 + wv * 64 + r8 * 8;
#pragma unroll
  for (int i = 0; i < 8; i++) {
    float4 s0 = make_float4(acc[i][0], acc[i][1], acc[i][2], acc[i][3]);
    float4 s1 = make_float4(acc[i][4], acc[i][5], acc[i][6], acc[i][7]);
    float* pp = pb + (b8 * 8 + i) * 256;
    *(float4*)pp = s0;
    *(float4*)(pp + 4) = s1;
  }
}

// Reduce partials: grid 512 = (kq 8) x (oq 64). hbuf[o] += sum_{kc in kq} part[kc][o]
__global__ __launch_bounds__(256) void k_r0red(const float* __restrict__ part,
    float* __restrict__ hbuf) {
  int blk = blockIdx.x;
  int oq = blk & 63, kq = blk >> 6;
  int o = oq * 256 + threadIdx.x;
  float s = 0.0f;
  const float* pp = part + kq * 64 * 16384 + o;
#pragma unroll 8
  for (int kc = 0; kc < 64; kc++) s += pp[kc * 16384];
  atomicAdd(&hbuf[o], s);
}

// grid 256 = (bb, pq): wt for 64 p's, partial res over those p's -> res4[pq][b][g]
__global__ __launch_bounds__(256) void k_wt_res(const float* __restrict__ hbuf,
    const float* __restrict__ r3_w, const float* __restrict__ r3_b,
    const float* __restrict__ yg, float* __restrict__ res4) {
  __shared__ float hs[256];
  __shared__ float wts[64];
  __shared__ float red[256];
  int blk = blockIdx.x;
  int bb = blk >> 2, pq = blk & 3;
  int t = threadIdx.x;
  float hv = hbuf[bb * 256 + t];
  hs[t] = hv > 0.0f ? hv : 0.01f * hv;
  __syncthreads();
  int pl = t >> 2, c = t & 3;
  int pp = pq * 64 + pl;
  const float4* wrow = (const float4*)(r3_w + pp * 256 + c * 64);
  const float4* h4 = (const float4*)(hs) + c * 16;
  float a = 0.0f;
#pragma unroll
  for (int j = 0; j < 16; j++) {
    float4 w4 = wrow[j], hh = h4[j];
    a += hh.x * w4.x + hh.y * w4.y + hh.z * w4.z + hh.w * w4.w;
  }
  a += __shfl_xor(a, 1);
  a += __shfl_xor(a, 2);
  if (c == 0) wts[pl] = fmaxf(a + r3_b[pp], 0.0f);
  __syncthreads();
  int g = t & 63, ch = t >> 6;
  float r = 0.0f;
  const float* ygp = yg + bb * 16384 + pq * 4096 + g;
#pragma unroll
  for (int pi = 0; pi < 16; pi++) {
    int pl2 = ch * 16 + pi;
    r += wts[pl2] * ygp[pl2 * 64];
  }
  red[t] = r;
  __syncthreads();
  if (t < 64)
    res4[pq * 4096 + bb * 64 + t] = red[t] + red[t + 64] + red[t + 128] + red[t + 192];
}

// z = elu([sum(res4), x2] @ l1_w^T + l1_b); out = z @ l3_w^T + l3_b
__global__ __launch_bounds__(128) void k_final(const float* __restrict__ res4,
    const float* __restrict__ x2, const float* __restrict__ l1_w,
    const float* __restrict__ l1_b, const float* __restrict__ l3_w,
    const float* __restrict__ l3_b, float* __restrict__ out) {
  __shared__ float zs[128];
  int bb = blockIdx.x, t = threadIdx.x;
  float acc = l1_b[t];
  const float* wrow = l1_w + t * 72;
  const float* rr = res4 + bb * 64;
#pragma unroll 8
  for (int j = 0; j < 64; j++) {
    float rv = rr[j] + rr[4096 + j] + rr[8192 + j] + rr[12288 + j];
    acc += rv * wrow[j];
  }
  const float* xr = x2 + bb * 8;
#pragma unroll
  for (int j = 0; j < 8; j++) acc += xr[j] * wrow[64 + j];
  zs[t] = acc > 0.0f ? acc : expm1f(acc);
  __syncthreads();
  if (t < 9) {
    float o = l3_b[t];
    const float* w3 = l3_w + t * 128;
    for (int j = 0; j < 128; j++) o += zs[j] * w3[j];
    out[bb * 9 + t] = o;
  }
}

extern "C" void kernel_launch(void* const* d_in, const int* in_sizes, int n_in,
                              void* d_out, int out_size, void* d_ws, size_t ws_size,
                              hipStream_t stream) {
  (void)in_sizes; (void)n_in; (void)out_size; (void)ws_size;
  const float* x1     = (const float*)d_in[0];
  const float* x2     = (const float*)d_in[1];
  const float* conv_w = (const float*)d_in[2];
  const float* conv_b = (const float*)d_in[3];
  const float* k1_w   = (const float*)d_in[4];
  const float* k1_b   = (const float*)d_in[5];
  const float* k2_w   = (const float*)d_in[6];
  const float* k3_w   = (const float*)d_in[7];
  const float* k4_w   = (const float*)d_in[8];
  const float* k5_w   = (const float*)d_in[9];
  const float* k5_b   = (const float*)d_in[10];
  const float* gc_w   = (const float*)d_in[11];
  const float* gc_b   = (const float*)d_in[12];
  const float* r0_w   = (const float*)d_in[13];
  const float* r1_w   = (const float*)d_in[14];
  const float* r1_b   = (const float*)d_in[15];
  const float* r2_w   = (const float*)d_in[16];
  const float* r3_w   = (const float*)d_in[17];
  const float* r3_b   = (const float*)d_in[18];
  const float* l1_w   = (const float*)d_in[19];
  const float* l1_b   = (const float*)d_in[20];
  const float* l3_w   = (const float*)d_in[21];
  const float* l3_b   = (const float*)d_in[22];
  const float* ef     = (const float*)d_in[23];
  const float* linc   = (const float*)d_in[24];
  const float* rinc   = (const float*)d_in[25];
  const float* cap    = (const float*)d_in[26];
  const int*   pidx   = (const int*)d_in[27];
  float* out = (float*)d_out;

  float* ws   = (float*)d_ws;
  float* xbuf = ws + X_OFF;
  float* t4   = ws + T4_OFF;
  float* t3   = ws + T3_OFF;
  float* kb   = ws + KB_OFF;
  float* kw_s = ws + KW_OFF;
  float* yg   = ws + YG_OFF;
  float* hbuf = ws + HB_OFF;
  float* res4 = ws + RES_OFF;
  float* part = ws + PART_OFF;
  int* ib = (int*)(ws + INT_OFF);
  int* lidx = ib;
  int* ridx = ib + 4096;
  int* part_start = ib + 8192;
  int* part_edges = ib + 8704;
  int* r_s = ib + 12800;

  hipLaunchKernelGGL(k_dc, dim3(3584), dim3(256), 0, stream,
                     linc, rinc, lidx, ridx, x1, conv_w, conv_b, xbuf);
  hipLaunchKernelGGL(k_lists, dim3(1), dim3(1024), 0, stream,
                     lidx, ridx, part_start, part_edges, r_s);
  hipLaunchKernelGGL(k_prep, dim3(1856), dim3(256), 0, stream,
                     xbuf, pidx, k3_w, k4_w, x2, k2_w, ef, k1_w, k1_b,
                     r1_w, r1_b, r2_w, cap, t4, t3, kb, hbuf);
  hipLaunchKernelGGL(k_edge, dim3(1024), dim3(256), 0, stream,
                     kb, t3, t4, k5_w, k5_b, lidx, ridx, part_edges, kw_s);
  hipLaunchKernelGGL(k_agg, dim3(1024), dim3(256), 0, stream,
                     xbuf, kw_s, r_s, part_start, gc_w, gc_b, yg);
  hipLaunchKernelGGL(k_r0, dim3(512), dim3(256), 0, stream, yg, r0_w, part);
  hipLaunchKernelGGL(k_r0red, dim3(512), dim3(256), 0, stream, part, hbuf);
  hipLaunchKernelGGL(k_wt_res, dim3(256), dim3(256), 0, stream, hbuf, r3_w, r3_b, yg, res4);
  hipLaunchKernelGGL(k_final, dim3(64), dim3(128), 0, stream,
                     res4, x2, l1_w, l1_b, l3_w, l3_b, out);
}

// Round 8
// 277.495 us; speedup vs baseline: 1.1011x; 1.1011x over previous
//
#include <hip/hip_runtime.h>
#include <math.h>

#define B_ 64
#define N_ 512
#define P_ 256
#define E_ 4096
#define F_ 32
#define H_ 64
#define W_ 8
#define G_ 64
#define RH_ 256

// ---- workspace layout (float offsets) ----
#define X_OFF   0
#define T4_OFF  (X_OFF + N_*B_*F_)       // x:  [n][b][f]
#define T3_OFF  (T4_OFF + N_*B_*H_)      // t4: [n][b][h] (t2 folded in)
#define KB_OFF  (T3_OFF + P_*B_*H_)      // t3: [p][b][h]
#define KW_OFF  (KB_OFF + E_*H_)         // kb: [e][h]
#define YG_OFF  (KW_OFF + E_*B_*W_)      // kw_s: [pos][b][w] (sorted by partition)
#define HB_OFF  (YG_OFF + B_*P_*G_)      // yg: [b][p*64+g]
#define RES_OFF (HB_OFF + B_*RH_)        // hbuf: [b][rh]
#define INT_OFF (RES_OFF + 4*B_*G_)      // res4: [pq][b][g]
#define PART_OFF (INT_OFF + 20480)       // r0 partials: [512][16384] floats
// int region at INT_OFF: lidx[4096] | ridx[4096] | part_start[512] | part_edges[4096] | r_s[4096]

// ---------------------------------------------------------------------------
// blocks [0,3072): decode one-hots; [3072,3584): grouped conv
__global__ __launch_bounds__(256) void k_dc(const float* __restrict__ linc,
    const float* __restrict__ rinc, int* __restrict__ lidx, int* __restrict__ ridx,
    const float* __restrict__ x1, const float* __restrict__ conv_w,
    const float* __restrict__ conv_b, float* __restrict__ x) {
  __shared__ float wsm[32 * 132];
  __shared__ float xsm[8192];
  int blk = blockIdx.x, t = threadIdx.x;
  if (blk < 3072) {
    int i4 = blk * 256 + t;
    const int L4 = (P_ * E_) / 4;  // 262144
    if (i4 < L4) {
      float4 v = ((const float4*)linc)[i4];
      int i = i4 * 4;
      int p = i >> 12, e = i & 4095;
      if (v.x != 0.0f) lidx[e]     = p;
      if (v.y != 0.0f) lidx[e + 1] = p;
      if (v.z != 0.0f) lidx[e + 2] = p;
      if (v.w != 0.0f) lidx[e + 3] = p;
    } else {
      int j4 = i4 - L4;
      float4 v = ((const float4*)rinc)[j4];
      int j = j4 * 4;
      int e = j >> 9, n = j & 511;
      if (v.x != 0.0f) ridx[e] = n;
      if (v.y != 0.0f) ridx[e] = n + 1;
      if (v.z != 0.0f) ridx[e] = n + 2;
      if (v.w != 0.0f) ridx[e] = n + 3;
    }
    return;
  }
  int n = blk - 3072;
  for (int i = t; i < 1024; i += 256) {
    int f = i >> 5, j = i & 31;
    ((float4*)wsm)[f * 33 + j] = ((const float4*)(conv_w + n * 4096))[i];
  }
  for (int i = t; i < 2048; i += 256) {
    int b = i >> 5, j = i & 31;
    ((float4*)xsm)[i] = ((const float4*)(x1 + b * 65536 + n * 128))[j];
  }
  __syncthreads();
  int f = t & 31, bq = t >> 5;
  float cb = conv_b[n * 32 + f];
  float acc[8];
#pragma unroll
  for (int bi = 0; bi < 8; bi++) acc[bi] = cb;
  const float4* wf4 = (const float4*)wsm + f * 33;
  const float4* xb4 = (const float4*)xsm + bq * 256;
#pragma unroll 4
  for (int k4 = 0; k4 < 32; k4++) {
    float4 wv = wf4[k4];
#pragma unroll
    for (int bi = 0; bi < 8; bi++) {
      float4 xv = xb4[bi * 32 + k4];
      acc[bi] += wv.x * xv.x + wv.y * xv.y + wv.z * xv.z + wv.w * xv.w;
    }
  }
#pragma unroll
  for (int bi = 0; bi < 8; bi++) {
    int b = bq * 8 + bi;
    x[n * 2048 + b * 32 + f] = fmaxf(acc[bi], 0.0f);
  }
}

// Counting-sort edges by partition; also emit r_s[pos] = ridx[part_edges[pos]].
__global__ __launch_bounds__(1024) void k_lists(const int* __restrict__ lidx,
    const int* __restrict__ ridx, int* __restrict__ part_start,
    int* __restrict__ part_edges, int* __restrict__ r_s) {
  __shared__ int cnt[256];
  __shared__ int buf[256];
  __shared__ int cur[256];
  int t = threadIdx.x;
  if (t < 256) cnt[t] = 0;
  __syncthreads();
  for (int e = t; e < E_; e += 1024) atomicAdd(&cnt[lidx[e]], 1);
  __syncthreads();
  if (t < 256) buf[t] = cnt[t];
  __syncthreads();
  for (int off = 1; off < 256; off <<= 1) {
    int add = 0;
    if (t < 256 && t >= off) add = buf[t - off];
    __syncthreads();
    if (t < 256) buf[t] += add;
    __syncthreads();
  }
  if (t < 256) {
    part_start[t + 1] = buf[t];
    if (t == 0) part_start[0] = 0;
    cur[t] = buf[t] - cnt[t];
  }
  __syncthreads();
  for (int e = t; e < E_; e += 1024) {
    int p = lidx[e];
    int pos = atomicAdd(&cur[p], 1);
    part_edges[pos] = e;
  }
  __syncthreads();
  for (int pos = t; pos < E_; pos += 1024) r_s[pos] = ridx[part_edges[pos]];
}

// blocks [0,512): t4[n][b][h] = x[n]@k4_w^T + x2@k2_w^T
// blocks [512,768): t3[p][b][h] = x[pidx[p]]@k3_w^T
// blocks [768,1792): kb[e][h] = ef[e,:8]@k1_w^T + k1_b
// blocks [1792,1856): hbuf[b][rh] = x2@r1_w^T + r1_b + cap@r2_w^T
__global__ __launch_bounds__(256) void k_prep(
    const float* __restrict__ x, const int* __restrict__ pidx,
    const float* __restrict__ k3_w, const float* __restrict__ k4_w,
    const float* __restrict__ x2, const float* __restrict__ k2_w,
    const float* __restrict__ ef, const float* __restrict__ k1_w,
    const float* __restrict__ k1_b,
    const float* __restrict__ r1_w, const float* __restrict__ r1_b,
    const float* __restrict__ r2_w, const float* __restrict__ cap,
    float* __restrict__ t4, float* __restrict__ t3, float* __restrict__ kb,
    float* __restrict__ hbuf) {
  __shared__ float xsh[2048];
  __shared__ float wsh[64 * 36];
  __shared__ float x2s[512];
  __shared__ float k2s[512];
  int blk = blockIdx.x, t = threadIdx.x;
  if (blk < 768) {
    bool isT4 = blk < 512;
    int n = isT4 ? blk : pidx[blk - 512];
    const float* wmat = isT4 ? k4_w : k3_w;
    float* outp = isT4 ? (t4 + blk * 4096) : (t3 + (blk - 512) * 4096);
    for (int i = t; i < 512; i += 256) {
      ((float4*)xsh)[i] = ((const float4*)(x + n * 2048))[i];
      int h = i >> 3, j = i & 7;
      ((float4*)wsh)[h * 9 + j] = ((const float4*)wmat)[i];
    }
    if (isT4) {
      for (int i = t; i < 128; i += 256) {
        ((float4*)x2s)[i] = ((const float4*)x2)[i];
        ((float4*)k2s)[i] = ((const float4*)k2_w)[i];
      }
    }
    __syncthreads();
    int h = t & 63, bq = t >> 6;
    float wreg[32];
#pragma unroll
    for (int j = 0; j < 8; j++) {
      float4 v = ((float4*)wsh)[h * 9 + j];
      wreg[4 * j] = v.x; wreg[4 * j + 1] = v.y; wreg[4 * j + 2] = v.z; wreg[4 * j + 3] = v.w;
    }
    float w2[8];
    if (isT4) {
      float4 u = ((float4*)k2s)[h * 2], v = ((float4*)k2s)[h * 2 + 1];
      w2[0] = u.x; w2[1] = u.y; w2[2] = u.z; w2[3] = u.w;
      w2[4] = v.x; w2[5] = v.y; w2[6] = v.z; w2[7] = v.w;
    }
    for (int bi = 0; bi < 16; bi++) {
      int b = bq * 16 + bi;
      float acc = 0.0f;
#pragma unroll
      for (int j = 0; j < 8; j++) {
        float4 xv = ((float4*)xsh)[b * 8 + j];
        acc += xv.x * wreg[4 * j] + xv.y * wreg[4 * j + 1] +
               xv.z * wreg[4 * j + 2] + xv.w * wreg[4 * j + 3];
      }
      if (isT4) {
        float4 u = ((float4*)x2s)[b * 2], v = ((float4*)x2s)[b * 2 + 1];
        acc += u.x * w2[0] + u.y * w2[1] + u.z * w2[2] + u.w * w2[3] +
               v.x * w2[4] + v.y * w2[5] + v.z * w2[6] + v.w * w2[7];
      }
      outp[b * 64 + h] = acc;
    }
  } else if (blk < 1792) {
    int o = (blk - 768) * 256 + t;
    int e = o >> 6, h = o & 63;
    float acc = k1_b[h];
    const float* er = ef + e * 9;
    const float* kr = k1_w + h * 8;
#pragma unroll
    for (int d = 0; d < 8; d++) acc += er[d] * kr[d];
    kb[o] = acc;
  } else {
    int o = (blk - 1792) * 256 + t;
    int rh = o & 255;
    float acc = r1_b[rh];
    const float* xr = x2 + (o >> 8) * 8;
    const float* rr = r1_w + rh * 8;
#pragma unroll
    for (int d = 0; d < 8; d++) acc += xr[d] * rr[d];
    const float* r2r = r2_w + rh * 256;
    for (int p4 = 0; p4 < 64; p4++) {
      float4 cv = ((const float4*)cap)[p4];
      float4 rv = ((const float4*)r2r)[p4];
      acc += cv.x * rv.x + cv.y * rv.y + cv.z * rv.z + cv.w * rv.w;
    }
    hbuf[o] = acc;
  }
}

// Phase A: per-edge kernel weights. 4 sorted positions per block.
// kern = kb[e]+t3[lidx]+t4[ridx]; leaky(0.02); @k5_w^T + k5_b; relu
// -> kw_s[pos][b][w] (partition-sorted order).
__global__ __launch_bounds__(256) void k_edge(
    const float* __restrict__ kb, const float* __restrict__ t3,
    const float* __restrict__ t4, const float* __restrict__ k5_w,
    const float* __restrict__ k5_b, const int* __restrict__ lidx,
    const int* __restrict__ ridx, const int* __restrict__ part_edges,
    float* __restrict__ kw_s) {
  __shared__ float k5t[4 * 520];
  int pos0 = blockIdx.x * 4, t = threadIdx.x;
  for (int i = t; i < 512; i += 256) {
    int h = i >> 3, w = i & 7;
    float v = k5_w[w * 64 + h];
#pragma unroll
    for (int qq = 0; qq < 4; qq++) k5t[qq * 520 + i] = v;
  }
  int q = t & 3, b = t >> 2;
  const float* kq = k5t + q * 520 + q * 128;
  float kb5_0 = k5_b[2 * q], kb5_1 = k5_b[2 * q + 1];
  __syncthreads();
  for (int ei = 0; ei < 4; ei++) {
    int pos = pos0 + ei;
    int e = part_edges[pos];
    int p = lidx[e], r = ridx[e];
    const float4* kb4 = (const float4*)(kb + e * 64 + q * 16);
    const float4* t34 = (const float4*)(t3 + p * 4096 + b * 64 + q * 16);
    const float4* t44 = (const float4*)(t4 + r * 4096 + b * 64 + q * 16);
    float lk[16];
#pragma unroll
    for (int j4 = 0; j4 < 4; j4++) {
      float4 a = kb4[j4], c = t34[j4], d = t44[j4];
      float v;
      v = a.x + c.x + d.x; lk[j4 * 4 + 0] = v > 0.0f ? v : 0.02f * v;
      v = a.y + c.y + d.y; lk[j4 * 4 + 1] = v > 0.0f ? v : 0.02f * v;
      v = a.z + c.z + d.z; lk[j4 * 4 + 2] = v > 0.0f ? v : 0.02f * v;
      v = a.w + c.w + d.w; lk[j4 * 4 + 3] = v > 0.0f ? v : 0.02f * v;
    }
    float pw[8] = {0, 0, 0, 0, 0, 0, 0, 0};
#pragma unroll
    for (int j = 0; j < 16; j++) {
      float4 u = *(const float4*)(kq + j * 8);
      float4 v = *(const float4*)(kq + j * 8 + 4);
      float l = lk[j];
      pw[0] += l * u.x; pw[1] += l * u.y; pw[2] += l * u.z; pw[3] += l * u.w;
      pw[4] += l * v.x; pw[5] += l * v.y; pw[6] += l * v.z; pw[7] += l * v.w;
    }
#pragma unroll
    for (int w = 0; w < 8; w++) {
      pw[w] += __shfl_xor(pw[w], 1);
      pw[w] += __shfl_xor(pw[w], 2);
    }
    float2 o;
    o.x = fmaxf(pw[2 * q] + kb5_0, 0.0f);
    o.y = fmaxf(pw[2 * q + 1] + kb5_1, 0.0f);
    *(float2*)(kw_s + pos * 512 + t * 2) = o;
  }
}

// Phase B: aggregation + gc GEMM. Grid 512 = bsub(2 hi) x p(256 lo); 32 b per block.
// Thread (bl = t>>3, fs = t&7) owns (b = bsub*32+bl, f-slice fs*4..fs*4+4, ALL 8 w):
// per edge = 1 dependent x float4 + 2 prefetched kw float4 + 32 FMA — x loaded
// exactly once per (b,f) (no w-redundancy). kw/r prefetch 1-deep (addresses are
// pos-sequential / independent of r). Epilogue: fp32 accS, phys_oct = oct^((bl>>2)&7)
// so the 8 q-row broadcast reads spread over all 32 banks.
__global__ __launch_bounds__(256) void k_agg(
    const float* __restrict__ x, const float* __restrict__ kw_s,
    const int* __restrict__ r_s, const int* __restrict__ part_start,
    const float* __restrict__ gc_w, const float* __restrict__ gc_b,
    float* __restrict__ yg) {
  __shared__ float accS[32 * 256];  // fp32 [bl][k]
  int blk = blockIdx.x, t = threadIdx.x;
  int p = blk & 255, bsub = blk >> 8;   // bsub in {0,1}
  int bl = t >> 3, fs = t & 7;
  int b = bsub * 32 + bl;
  float acc[8][4];
#pragma unroll
  for (int w = 0; w < 8; w++)
#pragma unroll
    for (int j = 0; j < 4; j++) acc[w][j] = 0.0f;
  int s0 = part_start[p], s1 = part_start[p + 1];
  const float* xb = x + b * 32 + fs * 4;
  const float* kwb = kw_s + b * 8;
  int r_cur = 0;
  float4 ka_cur = make_float4(0, 0, 0, 0), kc_cur = make_float4(0, 0, 0, 0);
  if (s0 < s1) {
    r_cur = r_s[s0];
    const float4* kp = (const float4*)(kwb + (size_t)s0 * 512);
    ka_cur = kp[0]; kc_cur = kp[1];
  }
  for (int pos = s0; pos < s1; pos++) {
    int r_n = r_cur;
    float4 ka_n = ka_cur, kc_n = kc_cur;
    if (pos + 1 < s1) {
      r_n = r_s[pos + 1];
      const float4* kp = (const float4*)(kwb + (size_t)(pos + 1) * 512);
      ka_n = kp[0]; kc_n = kp[1];
    }
    float4 xv = *(const float4*)(xb + r_cur * 2048);
    float kw[8] = {ka_cur.x, ka_cur.y, ka_cur.z, ka_cur.w,
                   kc_cur.x, kc_cur.y, kc_cur.z, kc_cur.w};
#pragma unroll
    for (int w = 0; w < 8; w++) {
      acc[w][0] += kw[w] * xv.x;
      acc[w][1] += kw[w] * xv.y;
      acc[w][2] += kw[w] * xv.z;
      acc[w][3] += kw[w] * xv.w;
    }
    r_cur = r_n; ka_cur = ka_n; kc_cur = kc_n;
  }
  // store acc -> accS: thread's quads qd = w*8+fs (k = w*32+fs*4), oct = w*4+(fs>>1)
  int swz = (bl >> 2) & 7;
#pragma unroll
  for (int w = 0; w < 8; w++) {
    int oct = w * 4 + (fs >> 1);
    int po = oct ^ swz;
    float* dst = accS + bl * 256 + po * 8 + (fs & 1) * 4;
    *(float4*)dst = make_float4(acc[w][0], acc[w][1], acc[w][2], acc[w][3]);
  }
  __syncthreads();
  // epilogue: wave wv -> g0 = wv*16 + gg*2; lane q = lane>>3 -> rows 4q..4q+3
  int lane = t & 63, wv = t >> 6;
  int q = lane >> 3, gg = lane & 7;
  int g0 = wv * 16 + gg * 2;
  const float* gw0 = gc_w + g0 * 256;
  const float* gw1 = gw0 + 256;
  float ac[4][2];
#pragma unroll
  for (int i = 0; i < 4; i++) { ac[i][0] = 0.0f; ac[i][1] = 0.0f; }
  for (int oct = 0; oct < 32; oct++) {
    int po = oct ^ q;  // rows 4q..4q+3 all have swz == q
    float4 b0a = *(const float4*)(gw0 + oct * 8);
    float4 b0b = *(const float4*)(gw0 + oct * 8 + 4);
    float4 b1a = *(const float4*)(gw1 + oct * 8);
    float4 b1b = *(const float4*)(gw1 + oct * 8 + 4);
    float bv0[8] = {b0a.x, b0a.y, b0a.z, b0a.w, b0b.x, b0b.y, b0b.z, b0b.w};
    float bv1[8] = {b1a.x, b1a.y, b1a.z, b1a.w, b1b.x, b1b.y, b1b.z, b1b.w};
#pragma unroll
    for (int i = 0; i < 4; i++) {
      const float* sp = accS + (4 * q + i) * 256 + po * 8;
      float4 aa = *(const float4*)sp;
      float4 ab = *(const float4*)(sp + 4);
      float av[8] = {aa.x, aa.y, aa.z, aa.w, ab.x, ab.y, ab.z, ab.w};
#pragma unroll
      for (int kk = 0; kk < 8; kk++) {
        ac[i][0] += av[kk] * bv0[kk];
        ac[i][1] += av[kk] * bv1[kk];
      }
    }
  }
  float gb0 = gc_b[g0], gb1 = gc_b[g0 + 1];
#pragma unroll
  for (int i = 0; i < 4; i++) {
    int bo = bsub * 32 + 4 * q + i;
    float2 o;
    o.x = fmaxf(ac[i][0] + gb0, 0.0f);
    o.y = fmaxf(ac[i][1] + gb1, 0.0f);
    *(float2*)(yg + bo * 16384 + p * 64 + g0) = o;
  }
}

// r0 GEMM partials: grid 512 = kc (Kc=32). Block computes full 64b x 256rh tile
// for its 32-k chunk via outer product; writes part[kc][b][rh].
__global__ __launch_bounds__(256) void k_r0(const float* __restrict__ yg,
    const float* __restrict__ r0_w, float* __restrict__ part) {
  __shared__ float ygs[32 * 69];   // ygT[k][b], row stride 69
  __shared__ float wts[32 * 260];  // wT[k][rh], row stride 260
  int kc = blockIdx.x, t = threadIdx.x;
  int k0 = kc * 32;
  {
    int c = t >> 5, rr = t & 31;
    for (int rd = 0; rd < 8; rd++) {
      int rh = rd * 32 + rr;
      float4 v = *(const float4*)(r0_w + rh * 16384 + k0 + c * 4);
      wts[(4 * c + 0) * 260 + rh] = v.x;
      wts[(4 * c + 1) * 260 + rh] = v.y;
      wts[(4 * c + 2) * 260 + rh] = v.z;
      wts[(4 * c + 3) * 260 + rh] = v.w;
    }
  }
  {
    int b = t >> 2, kq = t & 3;
    const float* src = yg + b * 16384 + k0 + kq * 8;
#pragma unroll
    for (int uu = 0; uu < 2; uu++) {
      float4 v = *(const float4*)(src + uu * 4);
      int kk = kq * 8 + uu * 4;
      ygs[(kk + 0) * 69 + b] = v.x;
      ygs[(kk + 1) * 69 + b] = v.y;
      ygs[(kk + 2) * 69 + b] = v.z;
      ygs[(kk + 3) * 69 + b] = v.w;
    }
  }
  __syncthreads();
  int lane = t & 63, wv = t >> 6;
  int b8 = lane & 7, r8 = lane >> 3;
  const float* yp = ygs + b8 * 8;
  const float* wp = wts + wv * 64 + r8 * 8;
  float acc[8][8];
#pragma unroll
  for (int i = 0; i < 8; i++)
#pragma unroll
    for (int j = 0; j < 8; j++) acc[i][j] = 0.0f;
#pragma unroll 2
  for (int k = 0; k < 32; k++) {
    float4 ya = *(const float4*)(yp + k * 69);
    float4 yb = *(const float4*)(yp + k * 69 + 4);
    float4 wa = *(const float4*)(wp + k * 260);
    float4 wb = *(const float4*)(wp + k * 260 + 4);
    float yv[8] = {ya.x, ya.y, ya.z, ya.w, yb.x, yb.y, yb.z, yb.w};
    float wr[8] = {wa.x, wa.y, wa.z, wa.w, wb.x, wb.y, wb.z, wb.w};
#pragma unroll
    for (int i = 0; i < 8; i++)
#pragma unroll
      for (int j = 0; j < 8; j++) acc[i][j] += yv[i] * wr[j];
  }
  float* pb = part + kc * 16384 + wv * 64 + r8 * 8;
#pragma unroll
  for (int i = 0; i < 8; i++) {
    float4 s0 = make_float4(acc[i][0], acc[i][1], acc[i][2], acc[i][3]);
    float4 s1 = make_float4(acc[i][4], acc[i][5], acc[i][6], acc[i][7]);
    float* pp = pb + (b8 * 8 + i) * 256;
    *(float4*)pp = s0;
    *(float4*)(pp + 4) = s1;
  }
}

// Reduce partials: grid 512 = (kq 8) x (oq 64). hbuf[o] += sum_{kc in kq} part[kc][o]
__global__ __launch_bounds__(256) void k_r0red(const float* __restrict__ part,
    float* __restrict__ hbuf) {
  int blk = blockIdx.x;
  int oq = blk & 63, kq = blk >> 6;
  int o = oq * 256 + threadIdx.x;
  float s = 0.0f;
  const float* pp = part + kq * 64 * 16384 + o;
#pragma unroll 8
  for (int kc = 0; kc < 64; kc++) s += pp[kc * 16384];
  atomicAdd(&hbuf[o], s);
}

// grid 256 = (bb, pq): wt for 64 p's, partial res over those p's -> res4[pq][b][g]
__global__ __launch_bounds__(256) void k_wt_res(const float* __restrict__ hbuf,
    const float* __restrict__ r3_w, const float* __restrict__ r3_b,
    const float* __restrict__ yg, float* __restrict__ res4) {
  __shared__ float hs[256];
  __shared__ float wts[64];
  __shared__ float red[256];
  int blk = blockIdx.x;
  int bb = blk >> 2, pq = blk & 3;
  int t = threadIdx.x;
  float hv = hbuf[bb * 256 + t];
  hs[t] = hv > 0.0f ? hv : 0.01f * hv;
  __syncthreads();
  int pl = t >> 2, c = t & 3;
  int pp = pq * 64 + pl;
  const float4* wrow = (const float4*)(r3_w + pp * 256 + c * 64);
  const float4* h4 = (const float4*)(hs) + c * 16;
  float a = 0.0f;
#pragma unroll
  for (int j = 0; j < 16; j++) {
    float4 w4 = wrow[j], hh = h4[j];
    a += hh.x * w4.x + hh.y * w4.y + hh.z * w4.z + hh.w * w4.w;
  }
  a += __shfl_xor(a, 1);
  a += __shfl_xor(a, 2);
  if (c == 0) wts[pl] = fmaxf(a + r3_b[pp], 0.0f);
  __syncthreads();
  int g = t & 63, ch = t >> 6;
  float r = 0.0f;
  const float* ygp = yg + bb * 16384 + pq * 4096 + g;
#pragma unroll
  for (int pi = 0; pi < 16; pi++) {
    int pl2 = ch * 16 + pi;
    r += wts[pl2] * ygp[pl2 * 64];
  }
  red[t] = r;
  __syncthreads();
  if (t < 64)
    res4[pq * 4096 + bb * 64 + t] = red[t] + red[t + 64] + red[t + 128] + red[t + 192];
}

// z = elu([sum(res4), x2] @ l1_w^T + l1_b); out = z @ l3_w^T + l3_b
__global__ __launch_bounds__(128) void k_final(const float* __restrict__ res4,
    const float* __restrict__ x2, const float* __restrict__ l1_w,
    const float* __restrict__ l1_b, const float* __restrict__ l3_w,
    const float* __restrict__ l3_b, float* __restrict__ out) {
  __shared__ float zs[128];
  int bb = blockIdx.x, t = threadIdx.x;
  float acc = l1_b[t];
  const float* wrow = l1_w + t * 72;
  const float* rr = res4 + bb * 64;
#pragma unroll 8
  for (int j = 0; j < 64; j++) {
    float rv = rr[j] + rr[4096 + j] + rr[8192 + j] + rr[12288 + j];
    acc += rv * wrow[j];
  }
  const float* xr = x2 + bb * 8;
#pragma unroll
  for (int j = 0; j < 8; j++) acc += xr[j] * wrow[64 + j];
  zs[t] = acc > 0.0f ? acc : expm1f(acc);
  __syncthreads();
  if (t < 9) {
    float o = l3_b[t];
    const float* w3 = l3_w + t * 128;
    for (int j = 0; j < 128; j++) o += zs[j] * w3[j];
    out[bb * 9 + t] = o;
  }
}

extern "C" void kernel_launch(void* const* d_in, const int* in_sizes, int n_in,
                              void* d_out, int out_size, void* d_ws, size_t ws_size,
                              hipStream_t stream) {
  (void)in_sizes; (void)n_in; (void)out_size; (void)ws_size;
  const float* x1     = (const float*)d_in[0];
  const float* x2     = (const float*)d_in[1];
  const float* conv_w = (const float*)d_in[2];
  const float* conv_b = (const float*)d_in[3];
  const float* k1_w   = (const float*)d_in[4];
  const float* k1_b   = (const float*)d_in[5];
  const float* k2_w   = (const float*)d_in[6];
  const float* k3_w   = (const float*)d_in[7];
  const float* k4_w   = (const float*)d_in[8];
  const float* k5_w   = (const float*)d_in[9];
  const float* k5_b   = (const float*)d_in[10];
  const float* gc_w   = (const float*)d_in[11];
  const float* gc_b   = (const float*)d_in[12];
  const float* r0_w   = (const float*)d_in[13];
  const float* r1_w   = (const float*)d_in[14];
  const float* r1_b   = (const float*)d_in[15];
  const float* r2_w   = (const float*)d_in[16];
  const float* r3_w   = (const float*)d_in[17];
  const float* r3_b   = (const float*)d_in[18];
  const float* l1_w   = (const float*)d_in[19];
  const float* l1_b   = (const float*)d_in[20];
  const float* l3_w   = (const float*)d_in[21];
  const float* l3_b   = (const float*)d_in[22];
  const float* ef     = (const float*)d_in[23];
  const float* linc   = (const float*)d_in[24];
  const float* rinc   = (const float*)d_in[25];
  const float* cap    = (const float*)d_in[26];
  const int*   pidx   = (const int*)d_in[27];
  float* out = (float*)d_out;

  float* ws   = (float*)d_ws;
  float* xbuf = ws + X_OFF;
  float* t4   = ws + T4_OFF;
  float* t3   = ws + T3_OFF;
  float* kb   = ws + KB_OFF;
  float* kw_s = ws + KW_OFF;
  float* yg   = ws + YG_OFF;
  float* hbuf = ws + HB_OFF;
  float* res4 = ws + RES_OFF;
  float* part = ws + PART_OFF;
  int* ib = (int*)(ws + INT_OFF);
  int* lidx = ib;
  int* ridx = ib + 4096;
  int* part_start = ib + 8192;
  int* part_edges = ib + 8704;
  int* r_s = ib + 12800;

  hipLaunchKernelGGL(k_dc, dim3(3584), dim3(256), 0, stream,
                     linc, rinc, lidx, ridx, x1, conv_w, conv_b, xbuf);
  hipLaunchKernelGGL(k_lists, dim3(1), dim3(1024), 0, stream,
                     lidx, ridx, part_start, part_edges, r_s);
  hipLaunchKernelGGL(k_prep, dim3(1856), dim3(256), 0, stream,
                     xbuf, pidx, k3_w, k4_w, x2, k2_w, ef, k1_w, k1_b,
                     r1_w, r1_b, r2_w, cap, t4, t3, kb, hbuf);
  hipLaunchKernelGGL(k_edge, dim3(1024), dim3(256), 0, stream,
                     kb, t3, t4, k5_w, k5_b, lidx, ridx, part_edges, kw_s);
  hipLaunchKernelGGL(k_agg, dim3(512), dim3(256), 0, stream,
                     xbuf, kw_s, r_s, part_start, gc_w, gc_b, yg);
  hipLaunchKernelGGL(k_r0, dim3(512), dim3(256), 0, stream, yg, r0_w, part);
  hipLaunchKernelGGL(k_r0red, dim3(512), dim3(256), 0, stream, part, hbuf);
  hipLaunchKernelGGL(k_wt_res, dim3(256), dim3(256), 0, stream, hbuf, r3_w, r3_b, yg, res4);
  hipLaunchKernelGGL(k_final, dim3(64), dim3(128), 0, stream,
                     res4, x2, l1_w, l1_b, l3_w, l3_b, out);
}